// Round 7
// baseline (235.770 us; speedup 1.0000x reference)
//
#include <hip/hip_runtime.h>
#include <math.h>

#define N_POINTS 4000000
#define N_PLANES 64
#define THRESH   0.02f
#define NVALS    (N_PLANES*10)     // 640
#define RBLOCKS  2048              // reduce grid cap (2560 B partial per block)
#define RTHREADS 256               // 4 waves per block
#define NCHUNK   (N_POINTS/64)     // 62500 chunks of exactly 64 points

// ---------------------------------------------------------------------------
// Stage 1: plane-per-lane moment reduction, vector-load + readlane broadcast.
// lane = plane id. A chunk = 64 consecutive points held point-per-lane in 3
// VGPRs (coalesced 12B/lane loads). Double-buffered chunks pipeline under
// vmcnt; each point is broadcast to all 64 lanes via v_readlane (SGPR) and
// feeds the 18-op predicated moment accumulation (one SGPR operand per FMA).
// ---------------------------------------------------------------------------
__device__ __forceinline__ float rlane(float v, int i) {
    return __uint_as_float(__builtin_amdgcn_readlane(__float_as_uint(v), i));
}
__device__ __forceinline__ unsigned uminu(unsigned a, unsigned b) {
    return a < b ? a : b;
}

struct Acc {
    float cnt, sx, sy, sz, xx, xy, xz, yy, yz, zz;
};

__device__ __forceinline__
void compute_chunk(float vx, float vy, float vz,
                   float nx, float ny, float nz, float nd, Acc& a)
{
#pragma unroll 1
    for (int g = 0; g < 64; g += 16) {      // keep body I$-sized; g is SALU-uniform
#pragma unroll
        for (int k = 0; k < 16; ++k) {
            const float x = rlane(vx, g + k);
            const float y = rlane(vy, g + k);
            const float z = rlane(vz, g + k);
            const float t  = fmaf(x, nx, fmaf(y, ny, fmaf(z, nz, nd)));
            const float fm = (fabsf(t) < THRESH) ? 1.0f : 0.0f;
            const float tx = fm * x, ty = fm * y, tz = fm * z;
            a.cnt += fm;
            a.sx += tx; a.sy += ty; a.sz += tz;
            a.xx = fmaf(tx, x, a.xx); a.xy = fmaf(tx, y, a.xy); a.xz = fmaf(tx, z, a.xz);
            a.yy = fmaf(ty, y, a.yy); a.yz = fmaf(ty, z, a.yz); a.zz = fmaf(tz, z, a.zz);
        }
    }
}

__global__ __launch_bounds__(RTHREADS)
void reduce_kernel(const float* __restrict__ pts,
                   const float* __restrict__ nrm,
                   const float* __restrict__ dst,
                   float* __restrict__ partials, int nwaves)
{
    const int lane = threadIdx.x & 63;
    const int wid  = threadIdx.x >> 6;
    const int w    = blockIdx.x * (RTHREADS/64) + wid;

    // per-lane plane parameters (lane == plane index)
    const float nx = nrm[lane*3+0];
    const float ny = nrm[lane*3+1];
    const float nz = nrm[lane*3+2];
    const float nd = -dst[lane];

    // contiguous chunk range for this wave
    const int cpw  = NCHUNK / nwaves;
    const int rem  = NCHUNK % nwaves;
    const int cbeg = w * cpw + (w < rem ? w : rem);
    const int cc   = cpw + (w < rem ? 1 : 0);

    Acc a = {0.f,0.f,0.f,0.f,0.f,0.f,0.f,0.f,0.f,0.f};

    const char* base = (const char*)pts;
    const unsigned offmax = (unsigned)(NCHUNK-1) * 768u + (unsigned)lane * 12u;
    unsigned offA = uminu((unsigned)cbeg * 768u + (unsigned)lane * 12u, offmax);

    float ax, ay, az, bx, by, bz;
    // prologue: load chunk cbeg into A
    ax = *(const float*)(base + offA + 0);
    ay = *(const float*)(base + offA + 4);
    az = *(const float*)(base + offA + 8);
    unsigned offB = uminu(offA + 768u, offmax);

    int c = 0;
    while (c + 2 <= cc) {
        // prefetch chunk c+1 into B (in range: c+1 <= cc-1)
        bx = *(const float*)(base + offB + 0);
        by = *(const float*)(base + offB + 4);
        bz = *(const float*)(base + offB + 8);
        compute_chunk(ax, ay, az, nx, ny, nz, nd, a);
        // prefetch chunk c+2 into A (clamped; wasted only on last iteration)
        const unsigned offA2 = uminu(offB + 768u, offmax);
        ax = *(const float*)(base + offA2 + 0);
        ay = *(const float*)(base + offA2 + 4);
        az = *(const float*)(base + offA2 + 8);
        compute_chunk(bx, by, bz, nx, ny, nz, nd, a);
        offA = offA2;
        offB = uminu(offA2 + 768u, offmax);
        c += 2;
    }
    if (c < cc)   // odd leftover chunk, already resident in A
        compute_chunk(ax, ay, az, nx, ny, nz, nd, a);

    // block combine: 4 per-wave rows -> 1 per-block row of 640 f32
    __shared__ float part[RTHREADS/64][NVALS];
    {
        float* r = &part[wid][lane * 10];
        r[0]=a.cnt; r[1]=a.sx; r[2]=a.sy; r[3]=a.sz;
        r[4]=a.xx;  r[5]=a.xy; r[6]=a.xz; r[7]=a.yy; r[8]=a.yz; r[9]=a.zz;
    }
    __syncthreads();
    for (int v = threadIdx.x; v < NVALS; v += RTHREADS) {
        float s = 0.f;
#pragma unroll
        for (int ww = 0; ww < RTHREADS/64; ++ww) s += part[ww][v];
        partials[(long long)blockIdx.x * NVALS + v] = s;
    }
}

// ---------------------------------------------------------------------------
// Stage 2 (fused fit): one block per plane. Stream partials, f64-accumulate,
// thread 0 runs the 3x3 Jacobi eigensolve and writes the merged param row:
//   {nx, ny, nz, -d, vld*rx, vld*ry, vld*rz, -vld*rd}
// ---------------------------------------------------------------------------
__global__ __launch_bounds__(256)
void finalize_kernel(const float* __restrict__ partials, int nb,
                     const float* __restrict__ nrm,
                     const float* __restrict__ dst,
                     float* __restrict__ params)
{
    const int p    = blockIdx.x;
    const int lane = threadIdx.x & 63;
    const int wid  = threadIdx.x >> 6;

    double s[10];
#pragma unroll
    for (int q = 0; q < 10; ++q) s[q] = 0.0;

    for (int b = threadIdx.x; b < nb; b += 256) {
        const float* row = partials + (long long)b * NVALS + p * 10;
#pragma unroll
        for (int q = 0; q < 10; ++q) s[q] += (double)row[q];
    }

#pragma unroll
    for (int off = 32; off; off >>= 1)
#pragma unroll
        for (int q = 0; q < 10; ++q) s[q] += __shfl_xor(s[q], off);

    __shared__ double wsum[4][10];
    if (lane == 0) {
#pragma unroll
        for (int q = 0; q < 10; ++q) wsum[wid][q] = s[q];
    }
    __syncthreads();
    if (threadIdx.x != 0) return;

    double acc[10];
#pragma unroll
    for (int q = 0; q < 10; ++q)
        acc[q] = wsum[0][q] + wsum[1][q] + wsum[2][q] + wsum[3][q];

    const double cnt = acc[0];
    const double sx = acc[1], sy = acc[2], sz = acc[3];
    const double den = fmax(cnt, 1.0);
    const double cx = sx / den, cy = sy / den, cz = sz / den;

    double C[3][3];
    C[0][0] = acc[4] - 2.0*cx*sx + cnt*cx*cx;
    C[0][1] = acc[5] - cx*sy - cy*sx + cnt*cx*cy;
    C[0][2] = acc[6] - cx*sz - cz*sx + cnt*cx*cz;
    C[1][1] = acc[7] - 2.0*cy*sy + cnt*cy*cy;
    C[1][2] = acc[8] - cy*sz - cz*sy + cnt*cy*cz;
    C[2][2] = acc[9] - 2.0*cz*sz + cnt*cz*cz;
    C[1][0] = C[0][1]; C[2][0] = C[0][2]; C[2][1] = C[1][2];

    const double valid = (cnt >= 3.0) ? 1.0 : 0.0;
    C[0][0] += (1.0 - valid) * 1.0;
    C[1][1] += (1.0 - valid) * 2.0;
    C[2][2] += (1.0 - valid) * 3.0;

    double V[3][3] = {{1,0,0},{0,1,0},{0,0,1}};
    for (int sweep = 0; sweep < 15; ++sweep) {
#pragma unroll
        for (int k = 0; k < 3; ++k) {
            const int pp = (k == 2) ? 1 : 0;
            const int qq = (k == 0) ? 1 : 2;
            const int rr = 3 - pp - qq;
            const double apq = C[pp][qq];
            if (fabs(apq) < 1e-300) continue;
            const double theta = (C[qq][qq] - C[pp][pp]) / (2.0 * apq);
            const double t = copysign(1.0, theta) / (fabs(theta) + sqrt(theta*theta + 1.0));
            const double c = 1.0 / sqrt(t*t + 1.0);
            const double ss = t * c;
            const double app = C[pp][pp], aqq = C[qq][qq];
            const double arp = C[rr][pp], arq = C[rr][qq];
            C[pp][pp] = app - t * apq;
            C[qq][qq] = aqq + t * apq;
            C[pp][qq] = 0.0; C[qq][pp] = 0.0;
            const double nrp = c*arp - ss*arq;
            const double nrq = ss*arp + c*arq;
            C[rr][pp] = nrp; C[pp][rr] = nrp;
            C[rr][qq] = nrq; C[qq][rr] = nrq;
#pragma unroll
            for (int i = 0; i < 3; ++i) {
                const double vip = V[i][pp], viq = V[i][qq];
                V[i][pp] = c*vip - ss*viq;
                V[i][qq] = ss*vip + c*viq;
            }
        }
    }

    int idx = 0;
    if (C[1][1] < C[idx][idx]) idx = 1;
    if (C[2][2] < C[idx][idx]) idx = 2;
    double rx = V[0][idx], ry = V[1][idx], rz = V[2][idx];
    const double inv = 1.0 / sqrt(rx*rx + ry*ry + rz*rz);
    rx *= inv; ry *= inv; rz *= inv;

    const double nxd = (double)nrm[p*3+0];
    const double nyd = (double)nrm[p*3+1];
    const double nzd = (double)nrm[p*3+2];
    if (rx*nxd + ry*nyd + rz*nzd < 0.0) { rx = -rx; ry = -ry; rz = -rz; }
    const double rd = cx*rx + cy*ry + cz*rz;

    const float vldf = (float)valid;
    params[p*8+0] = nrm[p*3+0];
    params[p*8+1] = nrm[p*3+1];
    params[p*8+2] = nrm[p*3+2];
    params[p*8+3] = -dst[p];
    params[p*8+4] = vldf * (float)rx;
    params[p*8+5] = vldf * (float)ry;
    params[p*8+6] = vldf * (float)rz;
    params[p*8+7] = -(vldf * (float)rd);
}

// ---------------------------------------------------------------------------
// Stage 3: projection, 4 points per thread (ILP + amortized param s_loads).
// Mask expression bit-identical to stage 1. vld folded into rv / rdv.
// ---------------------------------------------------------------------------
#define PPTH 4
#define PQ   (N_POINTS / PPTH)   // 1,000,000

__global__ __launch_bounds__(256)
void project_kernel(const float* __restrict__ pts,
                    const float* __restrict__ params,
                    float* __restrict__ out)
{
    const int tid = blockIdx.x * 256 + threadIdx.x;
    if (tid >= PQ) return;

    float ox[PPTH], oy[PPTH], oz[PPTH];
    float qx[PPTH], qy[PPTH], qz[PPTH];
#pragma unroll
    for (int k = 0; k < PPTH; ++k) {
        const long long i = (long long)tid + (long long)k * PQ;
        ox[k] = pts[i*3+0]; oy[k] = pts[i*3+1]; oz[k] = pts[i*3+2];
        qx[k] = ox[k]; qy[k] = oy[k]; qz[k] = oz[k];
    }

#pragma unroll 4
    for (int p = 0; p < N_PLANES; ++p) {
        const float nx  = params[p*8+0];
        const float ny  = params[p*8+1];
        const float nz  = params[p*8+2];
        const float md  = params[p*8+3];   // -d
        const float rvx = params[p*8+4];   // vld*rx
        const float rvy = params[p*8+5];
        const float rvz = params[p*8+6];
        const float mrd = params[p*8+7];   // -vld*rd

#pragma unroll
        for (int k = 0; k < PPTH; ++k) {
            const float t0 = fmaf(ox[k], nx, fmaf(oy[k], ny, fmaf(oz[k], nz, md)));
            const float t  = fmaf(qx[k], rvx, fmaf(qy[k], rvy, fmaf(qz[k], rvz, mrd)));
            const float tm = (fabsf(t0) < THRESH) ? t : 0.0f;
            qx[k] = fmaf(-tm, rvx, qx[k]);
            qy[k] = fmaf(-tm, rvy, qy[k]);
            qz[k] = fmaf(-tm, rvz, qz[k]);
        }
    }

#pragma unroll
    for (int k = 0; k < PPTH; ++k) {
        const long long i = (long long)tid + (long long)k * PQ;
        out[i*3+0] = qx[k];
        out[i*3+1] = qy[k];
        out[i*3+2] = qz[k];
    }
}

// ---------------------------------------------------------------------------
extern "C" void kernel_launch(void* const* d_in, const int* in_sizes, int n_in,
                              void* d_out, int out_size, void* d_ws, size_t ws_size,
                              hipStream_t stream)
{
    const float* pts = (const float*)d_in[0];
    const float* nrm = (const float*)d_in[1];
    const float* dst = (const float*)d_in[2];
    float* out = (float*)d_out;

    // size the reduce grid to the available scratch (2560 B per block row)
    size_t avail = (ws_size > 8192) ? (ws_size - 8192) : 0;
    int nb = (int)(avail / (NVALS * sizeof(float)));
    if (nb < 1) nb = 1;
    if (nb > RBLOCKS) nb = RBLOCKS;

    float* partials = (float*)d_ws;
    size_t poff = ((size_t)nb * NVALS * sizeof(float) + 255) & ~(size_t)255;
    float* params = (float*)((char*)d_ws + poff);

    const int nwaves = nb * (RTHREADS / 64);

    hipLaunchKernelGGL(reduce_kernel, dim3(nb), dim3(RTHREADS), 0, stream,
                       pts, nrm, dst, partials, nwaves);
    hipLaunchKernelGGL(finalize_kernel, dim3(N_PLANES), dim3(256), 0, stream,
                       partials, nb, nrm, dst, params);
    hipLaunchKernelGGL(project_kernel, dim3((PQ + 255) / 256), dim3(256), 0, stream,
                       pts, params, out);
}

// Round 8
// 208.569 us; speedup vs baseline: 1.1304x; 1.1304x over previous
//
#include <hip/hip_runtime.h>
#include <math.h>

#define N_POINTS 4000000
#define N_PLANES 64
#define THRESH   0.02f
#define NVALS    (N_PLANES*10)     // 640
#define RBLOCKS  2048              // reduce grid cap (2560 B partial per block)
#define RTHREADS 256               // 4 waves per block
#define NGROUPS  (N_POINTS/4)      // 1,000,000 groups of 4 points
#define TILE_G   64                // groups per LDS tile (256 points, 3072 B)
#define PTS_BYTES (N_POINTS*12)    // 48,000,000

// ---------------------------------------------------------------------------
// Stage 1: plane-per-lane moment reduction, LDS-broadcast point stream.
// lane = plane id. Each wave owns a contiguous range of 4-point groups.
// Points are staged into the wave's private LDS region (SoA X/Y/Z) with
// coalesced dwordx4 loads + 12 ds_write_b32; the compute loop reads 4 points
// per 3 x ds_read_b128 at a WAVE-UNIFORM address (hardware broadcast into
// VGPRs, LDS pipe, zero VALU broadcast cost). Next tile's global loads are
// register-prefetched under the current tile's compute.
// ---------------------------------------------------------------------------
__device__ __forceinline__ unsigned uminu(unsigned a, unsigned b) {
    return a < b ? a : b;
}

__device__ __forceinline__
void load_tile(const char* __restrict__ base, int tg, int lane, float4& d0, float4& d1, float4& d2)
{
    // tile dword span = [tg*12*4 bytes, +3072); round r, lane l -> byte tg*48 + r*1024 + l*16
    const unsigned b = (unsigned)tg * 48u + (unsigned)lane * 16u;
    d0 = *(const float4*)(base + uminu(b,          PTS_BYTES - 16u));
    d1 = *(const float4*)(base + uminu(b + 1024u,  PTS_BYTES - 16u));
    d2 = *(const float4*)(base + uminu(b + 2048u,  PTS_BYTES - 16u));
}

__global__ __launch_bounds__(RTHREADS)
void reduce_kernel(const float* __restrict__ pts,
                   const float* __restrict__ nrm,
                   const float* __restrict__ dst,
                   float* __restrict__ partials, int nwaves)
{
    const int lane = threadIdx.x & 63;
    const int wid  = threadIdx.x >> 6;
    const int w    = blockIdx.x * (RTHREADS/64) + wid;

    // per-lane plane parameters (lane == plane index)
    const float nx = nrm[lane*3+0];
    const float ny = nrm[lane*3+1];
    const float nz = nrm[lane*3+2];
    const float nd = -dst[lane];

    // contiguous group range for this wave
    const int gpw = NGROUPS / nwaves;
    const int rem = NGROUPS % nwaves;
    const int gb  = w * gpw + (w < rem ? w : rem);
    const int gc  = gpw + (w < rem ? 1 : 0);
    // uniform tile count across ALL waves (so __syncthreads never diverges)
    const int ntiles = (gpw + 1 + TILE_G - 1) / TILE_G;

    // LDS: per-wave staging region (768 floats: X[256] Y[256] Z[256]);
    // the partial-row buffer (4x640 floats) is ALIASED over it (barrier-separated).
    __shared__ float lds[4 * 768];
    float* const X = lds + wid * 768;
    float* const Y = X + 256;
    float* const Z = X + 512;

    // precompute the 12 LDS scatter indices for staging (lane-dependent, tile-invariant)
    int sidx[3][4];
#pragma unroll
    for (int r = 0; r < 3; ++r)
#pragma unroll
        for (int j = 0; j < 4; ++j) {
            const int g = r * 256 + lane * 4 + j;   // dword index within tile
            const int p = g / 3;                     // point
            const int c = g - 3 * p;                 // component
            sidx[r][j] = c * 256 + p;
        }

    float cnt=0.f, sx=0.f, sy=0.f, sz=0.f;
    float xx=0.f, xy=0.f, xz=0.f, yy=0.f, yz=0.f, zz=0.f;

    const char* base = (const char*)pts;
    float4 d0, d1, d2;
    load_tile(base, gb, lane, d0, d1, d2);          // prologue: tile 0

    for (int t = 0; t < ntiles; ++t) {
        const int tbeg = t * TILE_G;
        const int tgc  = (gc - tbeg < TILE_G) ? (gc - tbeg) : TILE_G;   // may be <=0

        __syncthreads();                             // prev tile's reads done (all waves)
        X[sidx[0][0]] = d0.x; X[sidx[0][1]] = d0.y; X[sidx[0][2]] = d0.z; X[sidx[0][3]] = d0.w;
        X[sidx[1][0]] = d1.x; X[sidx[1][1]] = d1.y; X[sidx[1][2]] = d1.z; X[sidx[1][3]] = d1.w;
        X[sidx[2][0]] = d2.x; X[sidx[2][1]] = d2.y; X[sidx[2][2]] = d2.z; X[sidx[2][3]] = d2.w;
        // register-prefetch next tile's global data (clamped; lands during compute)
        load_tile(base, gb + (t+1) * TILE_G, lane, d0, d1, d2);
        __syncthreads();                             // staging visible

#pragma unroll 2
        for (int i = 0; i < tgc; ++i) {
            const float4 xv = *(const float4*)(X + 4*i);   // uniform addr -> broadcast
            const float4 yv = *(const float4*)(Y + 4*i);
            const float4 zv = *(const float4*)(Z + 4*i);
#define MOM(xc, yc, zc)                                                        \
            {                                                                  \
                const float t_  = fmaf(xc, nx, fmaf(yc, ny, fmaf(zc, nz, nd)));\
                const bool  m_  = fabsf(t_) < THRESH;                          \
                const float fm_ = m_ ? 1.0f : 0.0f;                            \
                const float tx_ = m_ ? xc : 0.0f;                              \
                const float ty_ = m_ ? yc : 0.0f;                              \
                const float tz_ = m_ ? zc : 0.0f;                              \
                cnt += fm_;                                                    \
                sx += tx_; sy += ty_; sz += tz_;                               \
                xx = fmaf(tx_, xc, xx); xy = fmaf(tx_, yc, xy);                \
                xz = fmaf(tx_, zc, xz); yy = fmaf(ty_, yc, yy);                \
                yz = fmaf(ty_, zc, yz); zz = fmaf(tz_, zc, zz);                \
            }
            MOM(xv.x, yv.x, zv.x)
            MOM(xv.y, yv.y, zv.y)
            MOM(xv.z, yv.z, zv.z)
            MOM(xv.w, yv.w, zv.w)
#undef MOM
        }
    }

    // block combine (part buffer aliased over the staging LDS)
    __syncthreads();                                 // all compute reads done
    {
        float* r = lds + wid * NVALS + lane * 10;
        r[0]=cnt; r[1]=sx; r[2]=sy; r[3]=sz;
        r[4]=xx;  r[5]=xy; r[6]=xz; r[7]=yy; r[8]=yz; r[9]=zz;
    }
    __syncthreads();
    for (int v = threadIdx.x; v < NVALS; v += RTHREADS) {
        float s = 0.f;
#pragma unroll
        for (int ww = 0; ww < RTHREADS/64; ++ww) s += lds[ww * NVALS + v];
        partials[(long long)blockIdx.x * NVALS + v] = s;
    }
}

// ---------------------------------------------------------------------------
// Stage 2 (fused fit): one block per plane. Stream partials, f64-accumulate,
// thread 0 runs the 3x3 Jacobi eigensolve and writes the merged param row:
//   {nx, ny, nz, -d, vld*rx, vld*ry, vld*rz, -vld*rd}
// ---------------------------------------------------------------------------
__global__ __launch_bounds__(256)
void finalize_kernel(const float* __restrict__ partials, int nb,
                     const float* __restrict__ nrm,
                     const float* __restrict__ dst,
                     float* __restrict__ params)
{
    const int p    = blockIdx.x;
    const int lane = threadIdx.x & 63;
    const int wid  = threadIdx.x >> 6;

    double s[10];
#pragma unroll
    for (int q = 0; q < 10; ++q) s[q] = 0.0;

    for (int b = threadIdx.x; b < nb; b += 256) {
        const float* row = partials + (long long)b * NVALS + p * 10;
#pragma unroll
        for (int q = 0; q < 10; ++q) s[q] += (double)row[q];
    }

#pragma unroll
    for (int off = 32; off; off >>= 1)
#pragma unroll
        for (int q = 0; q < 10; ++q) s[q] += __shfl_xor(s[q], off);

    __shared__ double wsum[4][10];
    if (lane == 0) {
#pragma unroll
        for (int q = 0; q < 10; ++q) wsum[wid][q] = s[q];
    }
    __syncthreads();
    if (threadIdx.x != 0) return;

    double acc[10];
#pragma unroll
    for (int q = 0; q < 10; ++q)
        acc[q] = wsum[0][q] + wsum[1][q] + wsum[2][q] + wsum[3][q];

    const double cnt = acc[0];
    const double sx = acc[1], sy = acc[2], sz = acc[3];
    const double den = fmax(cnt, 1.0);
    const double cx = sx / den, cy = sy / den, cz = sz / den;

    double C[3][3];
    C[0][0] = acc[4] - 2.0*cx*sx + cnt*cx*cx;
    C[0][1] = acc[5] - cx*sy - cy*sx + cnt*cx*cy;
    C[0][2] = acc[6] - cx*sz - cz*sx + cnt*cx*cz;
    C[1][1] = acc[7] - 2.0*cy*sy + cnt*cy*cy;
    C[1][2] = acc[8] - cy*sz - cz*sy + cnt*cy*cz;
    C[2][2] = acc[9] - 2.0*cz*sz + cnt*cz*cz;
    C[1][0] = C[0][1]; C[2][0] = C[0][2]; C[2][1] = C[1][2];

    const double valid = (cnt >= 3.0) ? 1.0 : 0.0;
    C[0][0] += (1.0 - valid) * 1.0;
    C[1][1] += (1.0 - valid) * 2.0;
    C[2][2] += (1.0 - valid) * 3.0;

    double V[3][3] = {{1,0,0},{0,1,0},{0,0,1}};
    for (int sweep = 0; sweep < 15; ++sweep) {
#pragma unroll
        for (int k = 0; k < 3; ++k) {
            const int pp = (k == 2) ? 1 : 0;
            const int qq = (k == 0) ? 1 : 2;
            const int rr = 3 - pp - qq;
            const double apq = C[pp][qq];
            if (fabs(apq) < 1e-300) continue;
            const double theta = (C[qq][qq] - C[pp][pp]) / (2.0 * apq);
            const double t = copysign(1.0, theta) / (fabs(theta) + sqrt(theta*theta + 1.0));
            const double c = 1.0 / sqrt(t*t + 1.0);
            const double ss = t * c;
            const double app = C[pp][pp], aqq = C[qq][qq];
            const double arp = C[rr][pp], arq = C[rr][qq];
            C[pp][pp] = app - t * apq;
            C[qq][qq] = aqq + t * apq;
            C[pp][qq] = 0.0; C[qq][pp] = 0.0;
            const double nrp = c*arp - ss*arq;
            const double nrq = ss*arp + c*arq;
            C[rr][pp] = nrp; C[pp][rr] = nrp;
            C[rr][qq] = nrq; C[qq][rr] = nrq;
#pragma unroll
            for (int i = 0; i < 3; ++i) {
                const double vip = V[i][pp], viq = V[i][qq];
                V[i][pp] = c*vip - ss*viq;
                V[i][qq] = ss*vip + c*viq;
            }
        }
    }

    int idx = 0;
    if (C[1][1] < C[idx][idx]) idx = 1;
    if (C[2][2] < C[idx][idx]) idx = 2;
    double rx = V[0][idx], ry = V[1][idx], rz = V[2][idx];
    const double inv = 1.0 / sqrt(rx*rx + ry*ry + rz*rz);
    rx *= inv; ry *= inv; rz *= inv;

    const double nxd = (double)nrm[p*3+0];
    const double nyd = (double)nrm[p*3+1];
    const double nzd = (double)nrm[p*3+2];
    if (rx*nxd + ry*nyd + rz*nzd < 0.0) { rx = -rx; ry = -ry; rz = -rz; }
    const double rd = cx*rx + cy*ry + cz*rz;

    const float vldf = (float)valid;
    params[p*8+0] = nrm[p*3+0];
    params[p*8+1] = nrm[p*3+1];
    params[p*8+2] = nrm[p*3+2];
    params[p*8+3] = -dst[p];
    params[p*8+4] = vldf * (float)rx;
    params[p*8+5] = vldf * (float)ry;
    params[p*8+6] = vldf * (float)rz;
    params[p*8+7] = -(vldf * (float)rd);
}

// ---------------------------------------------------------------------------
// Stage 3: projection, 4 points per thread (ILP + amortized param s_loads).
// Mask expression bit-identical to stage 1. vld folded into rv / rdv.
// ---------------------------------------------------------------------------
#define PPTH 4
#define PQ   (N_POINTS / PPTH)   // 1,000,000

__global__ __launch_bounds__(256)
void project_kernel(const float* __restrict__ pts,
                    const float* __restrict__ params,
                    float* __restrict__ out)
{
    const int tid = blockIdx.x * 256 + threadIdx.x;
    if (tid >= PQ) return;

    float ox[PPTH], oy[PPTH], oz[PPTH];
    float qx[PPTH], qy[PPTH], qz[PPTH];
#pragma unroll
    for (int k = 0; k < PPTH; ++k) {
        const long long i = (long long)tid + (long long)k * PQ;
        ox[k] = pts[i*3+0]; oy[k] = pts[i*3+1]; oz[k] = pts[i*3+2];
        qx[k] = ox[k]; qy[k] = oy[k]; qz[k] = oz[k];
    }

#pragma unroll 4
    for (int p = 0; p < N_PLANES; ++p) {
        const float nx  = params[p*8+0];
        const float ny  = params[p*8+1];
        const float nz  = params[p*8+2];
        const float md  = params[p*8+3];   // -d
        const float rvx = params[p*8+4];   // vld*rx
        const float rvy = params[p*8+5];
        const float rvz = params[p*8+6];
        const float mrd = params[p*8+7];   // -vld*rd

#pragma unroll
        for (int k = 0; k < PPTH; ++k) {
            const float t0 = fmaf(ox[k], nx, fmaf(oy[k], ny, fmaf(oz[k], nz, md)));
            const float t  = fmaf(qx[k], rvx, fmaf(qy[k], rvy, fmaf(qz[k], rvz, mrd)));
            const float tm = (fabsf(t0) < THRESH) ? t : 0.0f;
            qx[k] = fmaf(-tm, rvx, qx[k]);
            qy[k] = fmaf(-tm, rvy, qy[k]);
            qz[k] = fmaf(-tm, rvz, qz[k]);
        }
    }

#pragma unroll
    for (int k = 0; k < PPTH; ++k) {
        const long long i = (long long)tid + (long long)k * PQ;
        out[i*3+0] = qx[k];
        out[i*3+1] = qy[k];
        out[i*3+2] = qz[k];
    }
}

// ---------------------------------------------------------------------------
extern "C" void kernel_launch(void* const* d_in, const int* in_sizes, int n_in,
                              void* d_out, int out_size, void* d_ws, size_t ws_size,
                              hipStream_t stream)
{
    const float* pts = (const float*)d_in[0];
    const float* nrm = (const float*)d_in[1];
    const float* dst = (const float*)d_in[2];
    float* out = (float*)d_out;

    // size the reduce grid to the available scratch (2560 B per block row)
    size_t avail = (ws_size > 8192) ? (ws_size - 8192) : 0;
    int nb = (int)(avail / (NVALS * sizeof(float)));
    if (nb < 1) nb = 1;
    if (nb > RBLOCKS) nb = RBLOCKS;

    float* partials = (float*)d_ws;
    size_t poff = ((size_t)nb * NVALS * sizeof(float) + 255) & ~(size_t)255;
    float* params = (float*)((char*)d_ws + poff);

    const int nwaves = nb * (RTHREADS / 64);

    hipLaunchKernelGGL(reduce_kernel, dim3(nb), dim3(RTHREADS), 0, stream,
                       pts, nrm, dst, partials, nwaves);
    hipLaunchKernelGGL(finalize_kernel, dim3(N_PLANES), dim3(256), 0, stream,
                       partials, nb, nrm, dst, params);
    hipLaunchKernelGGL(project_kernel, dim3((PQ + 255) / 256), dim3(256), 0, stream,
                       pts, params, out);
}

// Round 10
// 186.174 us; speedup vs baseline: 1.2664x; 1.1203x over previous
//
#include <hip/hip_runtime.h>
#include <math.h>

#define N_POINTS 4000000
#define N_PLANES 64
#define THRESH   0.02f
#define NVALS    (N_PLANES*10)              // 640
#define PPT      12                         // points per lane (register-resident)
#define BLKPTS   (PPT*64)                   // 768 points per point-block
#define NPB      ((N_POINTS + BLKPTS - 1)/BLKPTS)   // 5209 (last block: 256 valid)
#define NPAD     (NPB*BLKPTS - N_POINTS)    // 512 zero-padded points
#define SEG_R    16                         // rotations per work item (segment)
#define RBLK     2048                       // reduce grid (= partial rows)
#define RTHR     256                        // 4 waves per block

// ---------------------------------------------------------------------------
// Stage 1: systolic-rotation moment reduction. Lane l holds 12 points in
// VGPRs (loaded once, coalesced, double-buffered) and one resident plane
// (4 params + 10 f32 accumulators). Inner loop = pure 18-op VALU per point.
// Every SEG_R=16 point-passes the plane state rotates one lane over via
// 14 ds_bpermute_b32 (no broadcast reads, no butterflies, no atomics).
// The 4 waves of a block run complementary segments of the same 768-point
// block; block-level coverage: every (point, plane) pair exactly once.
// Tail block is ZERO-padded: pads contribute only to cnt (iff |d|<THRESH),
// which finalize subtracts exactly (NPAD * [|d_p| < THRESH]).
// ---------------------------------------------------------------------------
__device__ __forceinline__ float bperm(int addr, float v) {
    return __uint_as_float(__builtin_amdgcn_ds_bpermute(addr, __float_as_uint(v)));
}

__device__ __forceinline__
void load_pts(const float* __restrict__ pts, int pb, int lane,
              float (&X)[PPT], float (&Y)[PPT], float (&Z)[PPT])
{
    const int base = pb * BLKPTS + lane;
    if (pb != NPB - 1) {                         // wave-uniform branch
#pragma unroll
        for (int u = 0; u < PPT; ++u) {
            const float* P = pts + (long long)(base + u*64) * 3;
            X[u] = P[0]; Y[u] = P[1]; Z[u] = P[2];
        }
    } else {                                     // tail block: zero-pad invalid
#pragma unroll
        for (int u = 0; u < PPT; ++u) {
            const int i  = base + u*64;
            const int ic = (i < N_POINTS) ? i : 0;
            const float* P = pts + (long long)ic * 3;
            const float x = P[0], y = P[1], z = P[2];
            const bool v = i < N_POINTS;
            X[u] = v ? x : 0.0f;                 // (0,0,0): finite, only cnt-contaminating
            Y[u] = v ? y : 0.0f;
            Z[u] = v ? z : 0.0f;
        }
    }
}

__global__ __launch_bounds__(RTHR, 4)
void reduce_kernel(const float* __restrict__ pts,
                   const float* __restrict__ nrm,
                   const float* __restrict__ dst,
                   float* __restrict__ partials)
{
    const int lane = threadIdx.x & 63;
    const int wid  = threadIdx.x >> 6;

    __shared__ float part[RTHR/64][NVALS];
    for (int v = threadIdx.x; v < (RTHR/64)*NVALS; v += RTHR) (&part[0][0])[v] = 0.f;
    __syncthreads();

    const int rotaddr = ((lane + 1) & 63) << 2;   // pull from lane+1 (shift down)

    // resident plane params: start at segment wid; rotate continuously across
    // items (segment advances by 1 each item -> params land exactly where the
    // next item needs them; never reloaded).
    int s = wid;
    float cnx, cny, cnz, cnd;
    {
        const int q = (lane + SEG_R * s) & 63;
        cnx = nrm[q*3+0]; cny = nrm[q*3+1]; cnz = nrm[q*3+2]; cnd = -dst[q];
    }

    float PX[PPT], PY[PPT], PZ[PPT], QX[PPT], QY[PPT], QZ[PPT];
    load_pts(pts, blockIdx.x, lane, PX, PY, PZ);   // prologue

    for (int pb = blockIdx.x; pb < NPB; pb += RBLK) {
        const int pbn = (pb + RBLK < NPB) ? pb + RBLK : pb;
        load_pts(pts, pbn, lane, QX, QY, QZ);      // prefetch next item

        float a0=0.f,a1=0.f,a2=0.f,a3=0.f,a4=0.f,a5=0.f,a6=0.f,a7=0.f,a8=0.f,a9=0.f;

#pragma unroll 1
        for (int r = 0; r < SEG_R; ++r) {
#pragma unroll
            for (int u = 0; u < PPT; ++u) {
                const float x = PX[u], y = PY[u], z = PZ[u];
                const float t  = fmaf(x, cnx, fmaf(y, cny, fmaf(z, cnz, cnd)));
                const bool  m  = fabsf(t) < THRESH;
                const float fm = m ? 1.0f : 0.0f;
                const float tx = m ? x : 0.0f;
                const float ty = m ? y : 0.0f;
                const float tz = m ? z : 0.0f;
                a0 += fm;
                a1 += tx; a2 += ty; a3 += tz;
                a4 = fmaf(tx, x, a4); a5 = fmaf(tx, y, a5); a6 = fmaf(tx, z, a6);
                a7 = fmaf(ty, y, a7); a8 = fmaf(ty, z, a8); a9 = fmaf(tz, z, a9);
            }
            // rotate plane state one lane over (plane p: lane -> lane-1)
            cnx = bperm(rotaddr, cnx); cny = bperm(rotaddr, cny);
            cnz = bperm(rotaddr, cnz); cnd = bperm(rotaddr, cnd);
            a0 = bperm(rotaddr, a0); a1 = bperm(rotaddr, a1);
            a2 = bperm(rotaddr, a2); a3 = bperm(rotaddr, a3);
            a4 = bperm(rotaddr, a4); a5 = bperm(rotaddr, a5);
            a6 = bperm(rotaddr, a6); a7 = bperm(rotaddr, a7);
            a8 = bperm(rotaddr, a8); a9 = bperm(rotaddr, a9);
        }

        // lane l now holds the acc of plane (l + 16*(s+1)) & 63
        const int wp = (lane + SEG_R * (s + 1)) & 63;
        float* rr = &part[wid][wp * 10];
        rr[0]+=a0; rr[1]+=a1; rr[2]+=a2; rr[3]+=a3; rr[4]+=a4;
        rr[5]+=a5; rr[6]+=a6; rr[7]+=a7; rr[8]+=a8; rr[9]+=a9;

        s = (s + 1) & 3;
#pragma unroll
        for (int u = 0; u < PPT; ++u) { PX[u]=QX[u]; PY[u]=QY[u]; PZ[u]=QZ[u]; }
    }

    __syncthreads();
    for (int v = threadIdx.x; v < NVALS; v += RTHR) {
        float sum = 0.f;
#pragma unroll
        for (int ww = 0; ww < RTHR/64; ++ww) sum += part[ww][v];
        partials[(long long)blockIdx.x * NVALS + v] = sum;
    }
}

// ---------------------------------------------------------------------------
// Stage 2 (fused fit): one block per plane. Stream partials, f64-accumulate,
// subtract the deterministic zero-pad cnt contamination, then thread 0 runs
// the 3x3 Jacobi eigensolve and writes the merged param row:
//   {nx, ny, nz, -d, vld*rx, vld*ry, vld*rz, -vld*rd}
// ---------------------------------------------------------------------------
__global__ __launch_bounds__(256)
void finalize_kernel(const float* __restrict__ partials, int nb,
                     const float* __restrict__ nrm,
                     const float* __restrict__ dst,
                     float* __restrict__ params)
{
    const int p    = blockIdx.x;
    const int lane = threadIdx.x & 63;
    const int wid  = threadIdx.x >> 6;

    double s[10];
#pragma unroll
    for (int q = 0; q < 10; ++q) s[q] = 0.0;

    for (int b = threadIdx.x; b < nb; b += 256) {
        const float* row = partials + (long long)b * NVALS + p * 10;
#pragma unroll
        for (int q = 0; q < 10; ++q) s[q] += (double)row[q];
    }

#pragma unroll
    for (int off = 32; off; off >>= 1)
#pragma unroll
        for (int q = 0; q < 10; ++q) s[q] += __shfl_xor(s[q], off);

    __shared__ double wsum[4][10];
    if (lane == 0) {
#pragma unroll
        for (int q = 0; q < 10; ++q) wsum[wid][q] = s[q];
    }
    __syncthreads();
    if (threadIdx.x != 0) return;

    double acc[10];
#pragma unroll
    for (int q = 0; q < 10; ++q)
        acc[q] = wsum[0][q] + wsum[1][q] + wsum[2][q] + wsum[3][q];

    double cnt = acc[0];
    // exact removal of zero-pad contamination: each of the NPAD (0,0,0) pads
    // hit every plane once and contributed [ |-d_p| < THRESH ] to cnt only.
    if (fabsf(dst[p]) < THRESH) cnt -= (double)NPAD;

    const double sx = acc[1], sy = acc[2], sz = acc[3];
    const double den = fmax(cnt, 1.0);
    const double cx = sx / den, cy = sy / den, cz = sz / den;

    double C[3][3];
    C[0][0] = acc[4] - 2.0*cx*sx + cnt*cx*cx;
    C[0][1] = acc[5] - cx*sy - cy*sx + cnt*cx*cy;
    C[0][2] = acc[6] - cx*sz - cz*sx + cnt*cx*cz;
    C[1][1] = acc[7] - 2.0*cy*sy + cnt*cy*cy;
    C[1][2] = acc[8] - cy*sz - cz*sy + cnt*cy*cz;
    C[2][2] = acc[9] - 2.0*cz*sz + cnt*cz*cz;
    C[1][0] = C[0][1]; C[2][0] = C[0][2]; C[2][1] = C[1][2];

    const double valid = (cnt >= 3.0) ? 1.0 : 0.0;
    C[0][0] += (1.0 - valid) * 1.0;
    C[1][1] += (1.0 - valid) * 2.0;
    C[2][2] += (1.0 - valid) * 3.0;

    double V[3][3] = {{1,0,0},{0,1,0},{0,0,1}};
    for (int sweep = 0; sweep < 15; ++sweep) {
#pragma unroll
        for (int k = 0; k < 3; ++k) {
            const int pp = (k == 2) ? 1 : 0;
            const int qq = (k == 0) ? 1 : 2;
            const int rr = 3 - pp - qq;
            const double apq = C[pp][qq];
            if (fabs(apq) < 1e-300) continue;
            const double theta = (C[qq][qq] - C[pp][pp]) / (2.0 * apq);
            const double t = copysign(1.0, theta) / (fabs(theta) + sqrt(theta*theta + 1.0));
            const double c = 1.0 / sqrt(t*t + 1.0);
            const double ss = t * c;
            const double app = C[pp][pp], aqq = C[qq][qq];
            const double arp = C[rr][pp], arq = C[rr][qq];
            C[pp][pp] = app - t * apq;
            C[qq][qq] = aqq + t * apq;
            C[pp][qq] = 0.0; C[qq][pp] = 0.0;
            const double nrp = c*arp - ss*arq;
            const double nrq = ss*arp + c*arq;
            C[rr][pp] = nrp; C[pp][rr] = nrp;
            C[rr][qq] = nrq; C[qq][rr] = nrq;
#pragma unroll
            for (int i = 0; i < 3; ++i) {
                const double vip = V[i][pp], viq = V[i][qq];
                V[i][pp] = c*vip - ss*viq;
                V[i][qq] = ss*vip + c*viq;
            }
        }
    }

    int idx = 0;
    if (C[1][1] < C[idx][idx]) idx = 1;
    if (C[2][2] < C[idx][idx]) idx = 2;
    double rx = V[0][idx], ry = V[1][idx], rz = V[2][idx];
    const double inv = 1.0 / sqrt(rx*rx + ry*ry + rz*rz);
    rx *= inv; ry *= inv; rz *= inv;

    const double nxd = (double)nrm[p*3+0];
    const double nyd = (double)nrm[p*3+1];
    const double nzd = (double)nrm[p*3+2];
    if (rx*nxd + ry*nyd + rz*nzd < 0.0) { rx = -rx; ry = -ry; rz = -rz; }
    const double rd = cx*rx + cy*ry + cz*rz;

    const float vldf = (float)valid;
    params[p*8+0] = nrm[p*3+0];
    params[p*8+1] = nrm[p*3+1];
    params[p*8+2] = nrm[p*3+2];
    params[p*8+3] = -dst[p];
    params[p*8+4] = vldf * (float)rx;
    params[p*8+5] = vldf * (float)ry;
    params[p*8+6] = vldf * (float)rz;
    params[p*8+7] = -(vldf * (float)rd);
}

// ---------------------------------------------------------------------------
// Stage 3: projection, 4 points per thread (ILP + amortized param s_loads).
// Mask expression bit-identical to stage 1. vld folded into rv / rdv.
// ---------------------------------------------------------------------------
#define PPTH 4
#define PQ   (N_POINTS / PPTH)   // 1,000,000

__global__ __launch_bounds__(256)
void project_kernel(const float* __restrict__ pts,
                    const float* __restrict__ params,
                    float* __restrict__ out)
{
    const int tid = blockIdx.x * 256 + threadIdx.x;
    if (tid >= PQ) return;

    float ox[PPTH], oy[PPTH], oz[PPTH];
    float qx[PPTH], qy[PPTH], qz[PPTH];
#pragma unroll
    for (int k = 0; k < PPTH; ++k) {
        const long long i = (long long)tid + (long long)k * PQ;
        ox[k] = pts[i*3+0]; oy[k] = pts[i*3+1]; oz[k] = pts[i*3+2];
        qx[k] = ox[k]; qy[k] = oy[k]; qz[k] = oz[k];
    }

#pragma unroll 4
    for (int p = 0; p < N_PLANES; ++p) {
        const float nx  = params[p*8+0];
        const float ny  = params[p*8+1];
        const float nz  = params[p*8+2];
        const float md  = params[p*8+3];   // -d
        const float rvx = params[p*8+4];   // vld*rx
        const float rvy = params[p*8+5];
        const float rvz = params[p*8+6];
        const float mrd = params[p*8+7];   // -vld*rd

#pragma unroll
        for (int k = 0; k < PPTH; ++k) {
            const float t0 = fmaf(ox[k], nx, fmaf(oy[k], ny, fmaf(oz[k], nz, md)));
            const float t  = fmaf(qx[k], rvx, fmaf(qy[k], rvy, fmaf(qz[k], rvz, mrd)));
            const float tm = (fabsf(t0) < THRESH) ? t : 0.0f;
            qx[k] = fmaf(-tm, rvx, qx[k]);
            qy[k] = fmaf(-tm, rvy, qy[k]);
            qz[k] = fmaf(-tm, rvz, qz[k]);
        }
    }

#pragma unroll
    for (int k = 0; k < PPTH; ++k) {
        const long long i = (long long)tid + (long long)k * PQ;
        out[i*3+0] = qx[k];
        out[i*3+1] = qy[k];
        out[i*3+2] = qz[k];
    }
}

// ---------------------------------------------------------------------------
extern "C" void kernel_launch(void* const* d_in, const int* in_sizes, int n_in,
                              void* d_out, int out_size, void* d_ws, size_t ws_size,
                              hipStream_t stream)
{
    const float* pts = (const float*)d_in[0];
    const float* nrm = (const float*)d_in[1];
    const float* dst = (const float*)d_in[2];
    float* out = (float*)d_out;

    float* partials = (float*)d_ws;                         // RBLK x 640 f32 (5.24 MB)
    size_t poff = ((size_t)RBLK * NVALS * sizeof(float) + 255) & ~(size_t)255;
    float* params = (float*)((char*)d_ws + poff);

    hipLaunchKernelGGL(reduce_kernel, dim3(RBLK), dim3(RTHR), 0, stream,
                       pts, nrm, dst, partials);
    hipLaunchKernelGGL(finalize_kernel, dim3(N_PLANES), dim3(256), 0, stream,
                       partials, RBLK, nrm, dst, params);
    hipLaunchKernelGGL(project_kernel, dim3((PQ + 255) / 256), dim3(256), 0, stream,
                       pts, params, out);
}